// Round 3
// baseline (368.302 us; speedup 1.0000x reference)
//
#include <hip/hip_runtime.h>
#include <math.h>

#define KK 17
#define TT 512
#define DD 1024
#define NBATCH 64
#define NEGC -10000.0f
#define NINF -1e30f

__device__ __forceinline__ float wsum64(float v) {
#pragma unroll
  for (int s = 32; s >= 1; s >>= 1) v += __shfl_xor(v, s);
  return v;
}
__device__ __forceinline__ int wsum64i(int v) {
#pragma unroll
  for (int s = 32; s >= 1; s >>= 1) v += __shfl_xor(v, s);
  return v;
}
// readlane: VGPR lane -> SGPR broadcast, ~4 cyc, no LDS/lgkmcnt on the chain
__device__ __forceinline__ float rl(float x, int i) {
  return __int_as_float(__builtin_amdgcn_readlane(__float_as_int(x), i));
}

// ---------------- Kernel 1: logits = X @ W + b (unchanged, passed R2) ----------------
__global__ __launch_bounds__(512) void k_logits(const float* __restrict__ X,
                                                const float* __restrict__ W,
                                                const float* __restrict__ b,
                                                float* __restrict__ logits) {
  __shared__ float Ws[512 * KK];
  const int tid = threadIdx.x;
  const int lane = tid & 63;
  const int wv = tid >> 6;
  const long r0 = (long)blockIdx.x * 16 + wv * 2;
  const float* x0 = X + r0 * DD;
  float a0[KK], a1[KK];
#pragma unroll
  for (int j = 0; j < KK; ++j) { a0[j] = 0.f; a1[j] = 0.f; }

  for (int half = 0; half < 2; ++half) {
    __syncthreads();
#pragma unroll
    for (int i = 0; i < KK; ++i) {
      int idx = tid + i * 512;
      Ws[idx] = W[half * 512 * KK + idx];
    }
    __syncthreads();
#pragma unroll
    for (int it = 0; it < 8; ++it) {
      int k = it * 64 + lane;
      float xa = x0[half * 512 + k];
      float xb = x0[DD + half * 512 + k];
#pragma unroll
      for (int j = 0; j < KK; ++j) {
        float w = Ws[k * KK + j];
        a0[j] = fmaf(xa, w, a0[j]);
        a1[j] = fmaf(xb, w, a1[j]);
      }
    }
  }
#pragma unroll
  for (int j = 0; j < KK; ++j) { a0[j] = wsum64(a0[j]); a1[j] = wsum64(a1[j]); }
  if (lane < KK) {
    float v0 = 0.f, v1 = 0.f;
#pragma unroll
    for (int j = 0; j < KK; ++j)
      if (lane == j) { v0 = a0[j]; v1 = a1[j]; }
    float bb = b[lane];
    logits[r0 * KK + lane] = v0 + bb;
    logits[(r0 + 1) * KK + lane] = v1 + bb;
  }
}

// first-max select: strict '>' keeps LEFT (smaller indices) on ties == np.argmax
#define ARGM(vl, il, vr, ir, vo, io) \
  { bool tk = (vr) > (vl); vo = tk ? (vr) : (vl); io = tk ? (ir) : (il); }

// ---------------- Kernel 2: merged scans ----------------
// 64 blocks (one per batch) x 256 threads.
// wave0 = constrained viterbi, wave1 = scaled forward (logZ), wave2 = gold score,
// wave3 = staging help. Then all 256 threads: log-doubling backtrace + pred.
__global__ __launch_bounds__(256) void k_scan(
    const float* __restrict__ logits, const void* __restrict__ maskp,
    const int* __restrict__ gold, const float* __restrict__ trans,
    const float* __restrict__ st, const float* __restrict__ et,
    const float* __restrict__ ta, const float* __restrict__ sa,
    const float* __restrict__ ea, float* __restrict__ lossp,
    float* __restrict__ predp) {
  __shared__ __align__(16) float EM[513 * KK];  // RAW logits; +1 pad row
  __shared__ __align__(4) unsigned char Mk[512];
  __shared__ unsigned char BPt[511 * KK];
  __shared__ unsigned char G2t[256 * KK];
  __shared__ unsigned char G4t[128 * KK];
  __shared__ unsigned char G8t[64 * KK];
  __shared__ unsigned char PR[512];
  __shared__ float red[2];
  __shared__ int shlt;

  const int tid = threadIdx.x;
  const int lane = tid & 63;
  const int wv = tid >> 6;
  const int batch = blockIdx.x;
  const float* Lg = logits + (size_t)batch * TT * KK;

  // mask dtype detect: lengths>=128 so token 1 is masked-in. byte-bool -> byte1==1;
  // int32 -> byte1==0. Never OOB either way.
  const unsigned char* mb = (const unsigned char*)maskp;
  const bool m_is_i32 = (mb[1] == 0);

  // ---- stage raw emissions + mask (all 256 threads) ----
  {
    const float4* Lg4 = reinterpret_cast<const float4*>(Lg);
    float4* EM4 = reinterpret_cast<float4*>(EM);
    for (int i = tid; i < (TT * KK) / 4; i += 256) EM4[i] = Lg4[i];
    if (m_is_i32) {
      const int* mi = (const int*)maskp + batch * TT;
      for (int t2 = tid; t2 < TT; t2 += 256) Mk[t2] = (unsigned char)(mi[t2] != 0);
    } else {
      const unsigned char* mB = mb + batch * TT;
      for (int t2 = tid; t2 < TT; t2 += 256) Mk[t2] = (unsigned char)(mB[t2] != 0);
    }
  }
  __syncthreads();
  // ---- len (per-wave butterfly; mask is a contiguous prefix) ----
  int len;
  {
    const unsigned int* Mku = reinterpret_cast<const unsigned int*>(Mk);
    unsigned int a = Mku[lane], b2 = Mku[64 + lane];
    int c = (int)(((a * 0x01010101u) >> 24) + ((b2 * 0x01010101u) >> 24));
    len = wsum64i(c);
  }

  const int jc = lane < KK ? lane : (KK - 1);

  if (wv == 0) {
    // ---------- constrained viterbi: lane j owns v[j]; readlane broadcast ----------
    float ctv[KK];
#pragma unroll
    for (int i = 0; i < KK; ++i)
      ctv[i] = (ta[i * KK + jc] > 0.5f) ? trans[i * KK + jc] : NEGC;
    float v = ((sa[jc] > 0.5f) ? st[jc] : NEGC) + EM[jc];
    float ec = EM[KK + jc];
    const float* EMp = EM + 2 * KK + jc;
    unsigned char* bpw = BPt + jc;
    const bool act = lane < KK;
    for (int t = 1; t < len; ++t) {
      float en = *EMp;
      EMp += KK;
      float c0 = rl(v, 0) + ctv[0],  c1 = rl(v, 1) + ctv[1];
      float c2 = rl(v, 2) + ctv[2],  c3 = rl(v, 3) + ctv[3];
      float c4 = rl(v, 4) + ctv[4],  c5 = rl(v, 5) + ctv[5];
      float c6 = rl(v, 6) + ctv[6],  c7 = rl(v, 7) + ctv[7];
      float c8 = rl(v, 8) + ctv[8],  c9 = rl(v, 9) + ctv[9];
      float c10 = rl(v, 10) + ctv[10], c11 = rl(v, 11) + ctv[11];
      float c12 = rl(v, 12) + ctv[12], c13 = rl(v, 13) + ctv[13];
      float c14 = rl(v, 14) + ctv[14], c15 = rl(v, 15) + ctv[15];
      float c16 = rl(v, 16) + ctv[16];
      float d0, d1, d2, d3, d4, d5, d6, d7;
      int j0, j1, j2, j3, j4, j5, j6, j7;
      ARGM(c0, 0, c1, 1, d0, j0)     ARGM(c2, 2, c3, 3, d1, j1)
      ARGM(c4, 4, c5, 5, d2, j2)     ARGM(c6, 6, c7, 7, d3, j3)
      ARGM(c8, 8, c9, 9, d4, j4)     ARGM(c10, 10, c11, 11, d5, j5)
      ARGM(c12, 12, c13, 13, d6, j6) ARGM(c14, 14, c15, 15, d7, j7)
      float e0, e1, e2, e3; int k0, k1, k2, k3;
      ARGM(d0, j0, d1, j1, e0, k0)   ARGM(d2, j2, d3, j3, e1, k1)
      ARGM(d4, j4, d5, j5, e2, k2)   ARGM(d6, j6, d7, j7, e3, k3)
      float f0, f1; int l0, l1;
      ARGM(e0, k0, e1, k1, f0, l0)   ARGM(e2, k2, e3, k3, f1, l1)
      float g0; int m0i;
      ARGM(f0, l0, f1, l1, g0, m0i)
      float bv; int bi;
      ARGM(g0, m0i, c16, 16, bv, bi)
      if (act) bpw[0] = (unsigned char)bi;
      bpw += KK;
      v = bv + ec;
      ec = en;
    }
    // final argmax over lanes 0..16 (uniform via readlane, first-max)
    float fv = v + ((ea[jc] > 0.5f) ? et[jc] : NEGC);
    float best = rl(fv, 0);
    int bidx = 0;
#pragma unroll
    for (int i = 1; i < KK; ++i) {
      float fi = rl(fv, i);
      bool tk = fi > best;
      best = tk ? fi : best;
      bidx = tk ? i : bidx;
    }
    if (tid == 0) shlt = bidx;
  } else if (wv == 1) {
    // ---------- scaled forward (prob domain), readlane broadcast ----------
    float Pcol[KK];
#pragma unroll
    for (int i = 0; i < KK; ++i) Pcol[i] = __expf(trans[i * KK + jc]);
    float a0 = st[jc] + EM[jc];
    float m0 = rl(a0, 0);
#pragma unroll
    for (int i = 1; i < KK; ++i) m0 = fmaxf(m0, rl(a0, i));
    float qown = __expf(a0 - m0);
    float C = m0;
    float ee = __expf(EM[KK + jc]);  // exp(emit[1])
    const float* EMp = EM + 2 * KK + jc;
    for (int t = 1; t < len; ++t) {
      float en_raw = *EMp;
      EMp += KK;
      float q0 = rl(qown, 0), q1 = rl(qown, 1), q2 = rl(qown, 2), q3 = rl(qown, 3);
      float q4 = rl(qown, 4), q5 = rl(qown, 5), q6 = rl(qown, 6), q7 = rl(qown, 7);
      float q8 = rl(qown, 8), q9 = rl(qown, 9), q10 = rl(qown, 10), q11 = rl(qown, 11);
      float q12 = rl(qown, 12), q13 = rl(qown, 13), q14 = rl(qown, 14), q15 = rl(qown, 15);
      float q16 = rl(qown, 16);
      float da = fmaf(q0, Pcol[0], fmaf(q4, Pcol[4], fmaf(q8, Pcol[8], fmaf(q12, Pcol[12], q16 * Pcol[16]))));
      float db = fmaf(q1, Pcol[1], fmaf(q5, Pcol[5], fmaf(q9, Pcol[9], q13 * Pcol[13])));
      float dc = fmaf(q2, Pcol[2], fmaf(q6, Pcol[6], fmaf(q10, Pcol[10], q14 * Pcol[14])));
      float dd = fmaf(q3, Pcol[3], fmaf(q7, Pcol[7], fmaf(q11, Pcol[11], q15 * Pcol[15])));
      float qn = ((da + db) + (dc + dd)) * ee;
      ee = __expf(en_raw);
      if ((t & 7) == 0) {
        // renorm by PREVIOUS vector's sum (scalars already in hand; exact by linearity)
        float s0 = ((q0 + q1) + (q2 + q3)) + ((q4 + q5) + (q6 + q7));
        float s1 = ((q8 + q9) + (q10 + q11)) + ((q12 + q13) + (q14 + q15));
        float s = (s0 + s1) + q16;
        C += __logf(s);
        qn *= (1.0f / s);
      }
      qown = qn;
    }
    float term = qown * __expf(et[jc]);
    float S = rl(term, 0);
#pragma unroll
    for (int i = 1; i < KK; ++i) S += rl(term, i);
    if (lane == 0) red[0] = C + __logf(S);  // logZ
  } else if (wv == 2) {
    // ---------- gold path score ----------
    const int* gb = gold + batch * TT;
    float esum = 0.f, tsum = 0.f;
#pragma unroll
    for (int u = 0; u < 8; ++u) {
      int t = lane + 64 * u;
      int gt = gb[t];
      float mt = (float)Mk[t];
      esum += mt * EM[t * KK + gt];
      int tn = (t + 1 < TT) ? t + 1 : TT - 1;
      int gn = gb[tn];
      float mtr = (t + 1 < TT && Mk[t + 1]) ? 1.f : 0.f;
      tsum += mtr * trans[gt * KK + gn];
    }
    float ssum = wsum64(esum + tsum);
    if (lane == 0) red[1] = ssum + st[gb[0]] + et[gb[len - 1]];
  }
  __syncthreads();
  if (tid == 0) atomicAdd(lossp, red[0] - red[1]);  // loss = sum(logZ - score)

  const int lt = shlt;
  // ---- compose backpointer maps: g_s(x) = mask[s+1] ? bp[s][x] : x ----
  {
    int m = tid;  // 0..255
    int s1 = 2 * m + 1, s0b = 2 * m;
    bool u1 = (s1 < 511) && Mk[s1 + 1];
    bool u0 = Mk[s0b + 1] != 0;
#pragma unroll
    for (int x = 0; x < KK; ++x) {
      int y = u1 ? (int)BPt[s1 * KK + x] : x;
      int z = u0 ? (int)BPt[s0b * KK + y] : y;
      G2t[m * KK + x] = (unsigned char)z;
    }
  }
  __syncthreads();
  if (tid < 128) {
    int p = tid;
#pragma unroll
    for (int x = 0; x < KK; ++x) {
      int y = G2t[(2 * p + 1) * KK + x];
      G4t[p * KK + x] = G2t[2 * p * KK + y];
    }
  }
  __syncthreads();
  if (tid < 64) {
    int p = tid;
#pragma unroll
    for (int x = 0; x < KK; ++x) {
      int y = G4t[(2 * p + 1) * KK + x];
      G8t[p * KK + x] = G4t[2 * p * KK + y];
    }
  }
  __syncthreads();
  if (tid == 0) {  // serial chain: 64 dependent LDS lookups
    int x = lt;
    for (int p = 63; p >= 0; --p) {
      x = G8t[p * KK + x];
      PR[8 * p] = (unsigned char)x;
    }
  }
  __syncthreads();
  if (tid < 64) {
    int p = tid;
    int src = (p == 63) ? lt : (int)PR[8 * p + 8];
    PR[8 * p + 4] = G4t[(2 * p + 1) * KK + src];
  }
  __syncthreads();
  if (tid < 128) {
    int m = tid;
    int src = (m == 127) ? lt : (int)PR[4 * m + 4];
    PR[4 * m + 2] = G2t[(2 * m + 1) * KK + src];
  }
  __syncthreads();
  {
    int m = tid;  // 0..255
    int s = 2 * m + 1;
    int src = (m == 255) ? lt : (int)PR[2 * m + 2];
    int val = ((s < 511) && Mk[s + 1]) ? (int)BPt[s * KK + src] : src;
    PR[2 * m + 1] = (unsigned char)val;
  }
  __syncthreads();
  float* po = predp + batch * TT;
  for (int t2 = tid; t2 < TT; t2 += 256) po[t2] = Mk[t2] ? (float)PR[t2] : 0.f;
}

extern "C" void kernel_launch(void* const* d_in, const int* in_sizes, int n_in,
                              void* d_out, int out_size, void* d_ws, size_t ws_size,
                              hipStream_t stream) {
  const float* mlm = (const float*)d_in[0];
  const void* mask = d_in[1];
  const int* gold = (const int*)d_in[2];
  const float* W = (const float*)d_in[3];
  const float* b = (const float*)d_in[4];
  const float* trans = (const float*)d_in[5];
  const float* st = (const float*)d_in[6];
  const float* et = (const float*)d_in[7];
  const float* ta = (const float*)d_in[8];
  const float* sa = (const float*)d_in[9];
  const float* ea = (const float*)d_in[10];

  float* out = (float*)d_out;
  float* logits = out;                             // [64*512*17]
  float* lossp = out + (size_t)NBATCH * TT * KK;   // [1]
  float* predp = lossp + 1;                        // [64*512]

  hipMemsetAsync(lossp, 0, sizeof(float), stream);
  k_logits<<<dim3(2048), dim3(512), 0, stream>>>(mlm, W, b, logits);
  k_scan<<<dim3(64), dim3(256), 0, stream>>>(logits, mask, gold, trans, st, et,
                                             ta, sa, ea, lossp, predp);
}